// Round 1
// baseline (220.811 us; speedup 1.0000x reference)
//
#include <hip/hip_runtime.h>
#include <hip/hip_bf16.h>
#include <hip/hip_fp16.h>

#define N_NODES 50000
#define N_EDGES 400000
#define D 16
#define HID 64

#define SCAN_B 256
#define SCAN_G ((N_NODES + SCAN_B - 1) / SCAN_B)   // 196

typedef unsigned short ushort_t;
typedef _Float16 h16x2 __attribute__((ext_vector_type(2)));
typedef __attribute__((ext_vector_type(8))) short bf16x8_t;     // 8 bf16 (4 VGPRs)
typedef __attribute__((ext_vector_type(8))) _Float16 f16x8_t;   // 8 f16  (4 VGPRs)
typedef __attribute__((ext_vector_type(4))) float f32x4_t;      // MFMA acc

// ---------------- int-indexed workspace layout (CSR path) ----------------
#define CNT4_OFF  0                       // [4][N] replicated counts (memset to 0)
#define DEG_OFF   (4 * N_NODES)           // [N] total degree
#define OFF_OFF   (5 * N_NODES)           // [N+1] CSR offsets
#define CUR_OFF   (6 * N_NODES + 1)       // [N] claim cursors
#define BS_OFF    (7 * N_NODES + 1)       // [SCAN_G] block sums
#define MSG_OFF_I (((BS_OFF + SCAN_G) + 3) & ~3)  // [2E*16] fp32 msgs
#define CSR_NEEDED_BYTES ((size_t)(MSG_OFF_I + 2 * N_EDGES * D) * 4 + 64)

// ---------------- fallback (atomic) layout ----------------
#define FB_NDEG   (N_NODES)
#define FB_NACC   (N_NODES * D)
#define FB_FLAGS  (FB_NDEG + FB_NACC)

// ---------------- MFMA edge-kernel LDS layout (per wave, wave-private) ----
#define HSTRIDE 80                         // f16 elems per h row (16 rows)
#define VSTRIDE 36                         // f32 per v row (vs[16] | vd[16] | pad)
#define WAVE_H_BYTES (16 * HSTRIDE * 2)    // 2560
#define WAVE_V_BYTES (64 * VSTRIDE * 4)    // 9216
#define WAVE_LDS (WAVE_H_BYTES + WAVE_V_BYTES)  // 11776; x4 waves = 47104 B/block

// ---------------------------------------------------------------------------
// dtype helpers
// ---------------------------------------------------------------------------
__device__ __forceinline__ float bf_bits(ushort_t us) {
    return __uint_as_float(((unsigned)us) << 16);
}
__device__ __forceinline__ float lo_bf(unsigned u) { return __uint_as_float(u << 16); }
__device__ __forceinline__ float hi_bf(unsigned u) { return __uint_as_float(u & 0xffff0000u); }
__device__ __forceinline__ ushort_t f2bf(float v) {
    unsigned u = __float_as_uint(v);
    unsigned r = (u + 0x7fffu + ((u >> 16) & 1u)) >> 16;
    return (ushort_t)r;
}
__device__ __forceinline__ float ld_f(const void* p, int idx, int f32) {
    return f32 ? ((const float*)p)[idx]
               : bf_bits(((const ushort_t*)p)[idx]);
}

__device__ __forceinline__ unsigned pack_h2(float a, float b) {
#if __has_builtin(__builtin_amdgcn_cvt_pkrtz)
    return __builtin_bit_cast(unsigned, __builtin_amdgcn_cvt_pkrtz(a, b));
#else
    h16x2 h;
    h.x = (_Float16)a;
    h.y = (_Float16)b;
    return __builtin_bit_cast(unsigned, h);
#endif
}

__device__ __forceinline__ void load16(const void* __restrict__ p, long long base,
                                       int f32, float* o) {
    if (f32) {
        const float4* q = (const float4*)((const float*)p + base);
        float4 a = q[0], b = q[1], c = q[2], d = q[3];
        o[0]=a.x; o[1]=a.y; o[2]=a.z; o[3]=a.w;
        o[4]=b.x; o[5]=b.y; o[6]=b.z; o[7]=b.w;
        o[8]=c.x; o[9]=c.y; o[10]=c.z; o[11]=c.w;
        o[12]=d.x; o[13]=d.y; o[14]=d.z; o[15]=d.w;
    } else {
        const uint4* q = (const uint4*)((const ushort_t*)p + base);
        uint4 a = q[0], b = q[1];
        unsigned u[8] = {a.x, a.y, a.z, a.w, b.x, b.y, b.z, b.w};
#pragma unroll
        for (int k = 0; k < 8; k++) {
            o[2 * k]     = lo_bf(u[k]);
            o[2 * k + 1] = hi_bf(u[k]);
        }
    }
}

__device__ __forceinline__ void load_edge(const void* __restrict__ ei, int e, int is64,
                                          int& s, int& d) {
    if (is64) {
        const long long* p = (const long long*)ei;
        s = (int)p[e];
        d = (int)p[N_EDGES + e];
    } else {
        const int* p = (const int*)ei;
        s = p[e];
        d = p[N_EDGES + e];
    }
}

__device__ __forceinline__ void detect_flags(const void* x, const void* ei, int* flags) {
    const ushort_t* h = (const ushort_t*)x;
    int f32 = 0;
    for (int k = 0; k < 256; k++) {
        float v = bf_bits(h[k]);
        if (!(v == v) || fabsf(v) > 1.0e6f) { f32 = 1; break; }
    }
    const long long* p = (const long long*)ei;
    int i64 = 1;
    for (int k = 0; k < 16; k++) {
        long long v = p[k];
        if (v < 0 || v >= N_NODES) { i64 = 0; break; }
    }
    flags[0] = f32;
    flags[1] = i64;
}

__device__ __forceinline__ void stage_weights(
    const void* W1, const void* b1, const void* W2, const void* b2, int f32,
    float* sW1, float* sW2t, float* sb1, float* sb2)
{
    int t = threadIdx.x;
    for (int idx = t; idx < HID * 2 * D; idx += blockDim.x)
        sW1[idx] = ld_f(W1, idx, f32);
    for (int idx = t; idx < HID * D; idx += blockDim.x) {
        int j = idx / D, i = idx % D;
        sW2t[idx] = ld_f(W2, i * HID + j, f32);
    }
    if (t < HID) sb1[t] = ld_f(b1, t, f32);
    if (t < D)  sb2[t] = ld_f(b2, t, f32);
}

// ---------------------------------------------------------------------------
// Full-MLP per-edge math, f32 (safety + fallback paths)
// ---------------------------------------------------------------------------
__device__ __forceinline__ void edge_math_v4(
    const float* __restrict__ sW1, const float* __restrict__ sW2t,
    const float* __restrict__ sb1, const float* __restrict__ sb2,
    const float* xs, const float* xd, float coef,
    float* ms, float* md)
{
    float vs[D], vd[D];
#pragma unroll
    for (int i = 0; i < D; i++) { vs[i] = sb2[i]; vd[i] = sb2[i]; }
#pragma unroll 4
    for (int j = 0; j < HID; j++) {
        float hs = sb1[j], hd = sb1[j];
        const float4* w4 = (const float4*)&sW1[j * 2 * D];
#pragma unroll
        for (int t = 0; t < 4; t++) {
            float4 wv = w4[t];
            int k = 4 * t;
            hs = fmaf(wv.x, xs[k],     hs); hd = fmaf(wv.x, xd[k],     hd);
            hs = fmaf(wv.y, xs[k + 1], hs); hd = fmaf(wv.y, xd[k + 1], hd);
            hs = fmaf(wv.z, xs[k + 2], hs); hd = fmaf(wv.z, xd[k + 2], hd);
            hs = fmaf(wv.w, xs[k + 3], hs); hd = fmaf(wv.w, xd[k + 3], hd);
        }
#pragma unroll
        for (int t = 0; t < 4; t++) {
            float4 wv = w4[4 + t];
            int k = 4 * t;
            hs = fmaf(wv.x, xd[k],     hs); hd = fmaf(wv.x, xs[k],     hd);
            hs = fmaf(wv.y, xd[k + 1], hs); hd = fmaf(wv.y, xs[k + 1], hd);
            hs = fmaf(wv.z, xd[k + 2], hs); hd = fmaf(wv.z, xs[k + 2], hd);
            hs = fmaf(wv.w, xd[k + 3], hs); hd = fmaf(wv.w, xs[k + 3], hd);
        }
        hs = fmaxf(hs, 0.0f);
        hd = fmaxf(hd, 0.0f);
        const float4* w24 = (const float4*)&sW2t[j * D];
#pragma unroll
        for (int t = 0; t < 4; t++) {
            float4 u = w24[t];
            int i = 4 * t;
            vs[i]     = fmaf(u.x, hs, vs[i]);     vd[i]     = fmaf(u.x, hd, vd[i]);
            vs[i + 1] = fmaf(u.y, hs, vs[i + 1]); vd[i + 1] = fmaf(u.y, hd, vd[i + 1]);
            vs[i + 2] = fmaf(u.z, hs, vs[i + 2]); vd[i + 2] = fmaf(u.z, hd, vd[i + 2]);
            vs[i + 3] = fmaf(u.w, hs, vs[i + 3]); vd[i + 3] = fmaf(u.w, hd, vd[i + 3]);
        }
    }
    float ns = 0.0f, nd = 0.0f;
#pragma unroll
    for (int i = 0; i < D; i++) { ns = fmaf(vs[i], vs[i], ns); nd = fmaf(vd[i], vd[i], nd); }
    float is_ = 1.0f / fmaxf(sqrtf(ns), 1e-12f);
    float id_ = 1.0f / fmaxf(sqrtf(nd), 1e-12f);
#pragma unroll
    for (int i = 0; i < D; i++) { vs[i] *= is_; vd[i] *= id_; }
    float dot1 = 0.0f;
#pragma unroll
    for (int i = 0; i < D; i++) dot1 = fmaf(vd[i], xd[i], dot1);
#pragma unroll
    for (int i = 0; i < D; i++) ms[i] = fmaf(-2.0f * dot1, vd[i], xd[i]);
    float dot2 = 0.0f;
#pragma unroll
    for (int i = 0; i < D; i++) dot2 = fmaf(vs[i], ms[i], dot2);
#pragma unroll
    for (int i = 0; i < D; i++) ms[i] = coef * fmaf(-2.0f * dot2, vs[i], ms[i]);
    float dot3 = 0.0f;
#pragma unroll
    for (int i = 0; i < D; i++) dot3 = fmaf(vs[i], xs[i], dot3);
#pragma unroll
    for (int i = 0; i < D; i++) md[i] = fmaf(-2.0f * dot3, vs[i], xs[i]);
    float dot4 = 0.0f;
#pragma unroll
    for (int i = 0; i < D; i++) dot4 = fmaf(vd[i], md[i], dot4);
#pragma unroll
    for (int i = 0; i < D; i++) md[i] = coef * fmaf(-2.0f * dot4, vd[i], md[i]);
}

// ===========================================================================
// CSR path kernels
// ===========================================================================
__global__ void csr_count_kernel(const void* __restrict__ ei,
                                 const void* __restrict__ x,
                                 int* __restrict__ wsI) {
    __shared__ int sfl[2];
    if (threadIdx.x == 0) detect_flags(x, ei, sfl);
    __syncthreads();
    int i64 = sfl[1];
    int e = blockIdx.x * blockDim.x + threadIdx.x;
    if (e >= N_EDGES) return;
    int s, d;
    load_edge(ei, e, i64, s, d);
    int r = (e & 3) * N_NODES;
    atomicAdd(&wsI[CNT4_OFF + r + s], 1);
    atomicAdd(&wsI[CNT4_OFF + r + d], 1);
}

__global__ __launch_bounds__(SCAN_B) void csr_scan1_kernel(int* __restrict__ wsI) {
    __shared__ int sm[SCAN_B];
    int t = threadIdx.x;
    int g = blockIdx.x * SCAN_B + t;
    int c = 0;
    if (g < N_NODES) {
        c = wsI[CNT4_OFF + g] + wsI[CNT4_OFF + N_NODES + g]
          + wsI[CNT4_OFF + 2 * N_NODES + g] + wsI[CNT4_OFF + 3 * N_NODES + g];
        wsI[DEG_OFF + g] = c;
    }
    sm[t] = c;
    __syncthreads();
    for (int st = SCAN_B / 2; st > 0; st >>= 1) {
        if (t < st) sm[t] += sm[t + st];
        __syncthreads();
    }
    if (t == 0) wsI[BS_OFF + blockIdx.x] = sm[0];
}

__global__ __launch_bounds__(SCAN_B) void csr_scan3_kernel(int* __restrict__ wsI) {
    __shared__ int sB[SCAN_B];
    __shared__ int sm[SCAN_B];
    int t = threadIdx.x;
    int bsv = (t < SCAN_G) ? wsI[BS_OFF + t] : 0;
    sB[t] = bsv;
    __syncthreads();
    for (int st = 1; st < SCAN_B; st <<= 1) {
        int u = (t >= st) ? sB[t - st] : 0;
        __syncthreads();
        sB[t] += u;
        __syncthreads();
    }
    int blockBase = sB[blockIdx.x] - wsI[BS_OFF + blockIdx.x];

    int g = blockIdx.x * SCAN_B + t;
    int c = (g < N_NODES) ? wsI[DEG_OFF + g] : 0;
    sm[t] = c;
    __syncthreads();
    for (int st = 1; st < SCAN_B; st <<= 1) {
        int u = (t >= st) ? sm[t - st] : 0;
        __syncthreads();
        sm[t] += u;
        __syncthreads();
    }
    int excl = sm[t] - c + blockBase;
    if (g < N_NODES) {
        wsI[OFF_OFF + g] = excl;
        wsI[CUR_OFF + g] = excl;
        if (g == N_NODES - 1) wsI[OFF_OFF + N_NODES] = excl + c;
    }
}

// ---------------------------------------------------------------------------
// Edge kernel, MFMA formulation (bf16 path).
// Per wave: 64 edges as 4 groups of 16 rows.
//   GEMM1: [16 x 32]([xs|xd], bf16 direct-gather A-frag) @ W1^T -> h [16 x 64]
//          reversed tile via B1s = W1 with K-halves swapped (no 2nd gather).
//   h -> f16 -> wave-private LDS -> A-frags -> GEMM2 (f16): v [16 x 16]
//   v accumulated in wave-private LDS; epilogue thread-per-edge reuses the
//   proven scalar Householder/coef/claim/store code.
// No barriers in main path (all LDS wave-private; same-wave DS ops are ordered).
// ---------------------------------------------------------------------------
__global__ __launch_bounds__(256) void csr_edge_kernel(
    const void* __restrict__ x,
    const void* __restrict__ ei,
    const void* __restrict__ W1,
    const void* __restrict__ b1,
    const void* __restrict__ W2,
    const void* __restrict__ b2,
    int* __restrict__ wsI)
{
    __shared__ __align__(16) char smem[4 * WAVE_LDS];   // 47104 B (union w/ f32 path)
    __shared__ int sfl[2];
    if (threadIdx.x == 0) detect_flags(x, ei, sfl);
    __syncthreads();
    int f32 = sfl[0], i64 = sfl[1];
    int t = threadIdx.x;
    float* msg = (float*)(wsI + MSG_OFF_I);

    if (f32) {
        // ---------------- f32 safety path (unchanged math) ----------------
        float* sW1f  = (float*)smem;                 // [HID*2D]
        float* sW2tf = sW1f + HID * 2 * D;           // [HID*D]
        float* sb1   = sW2tf + HID * D;              // [HID]
        float* sb2   = sb1 + HID;                    // [D]
        for (int idx = t; idx < HID * 2 * D; idx += 256)
            sW1f[idx] = ((const float*)W1)[idx];
        for (int idx = t; idx < HID * D; idx += 256) {
            int j = idx / D, i = idx % D;
            sW2tf[idx] = ((const float*)W2)[i * HID + j];
        }
        if (t < HID) sb1[t] = ((const float*)b1)[t];
        if (t < D)  sb2[t] = ((const float*)b2)[t];
        __syncthreads();

        int e = blockIdx.x * 256 + t;
        if (e >= N_EDGES) return;
        int s, d;
        load_edge(ei, e, i64, s, d);
        float degs = (float)wsI[DEG_OFF + s];
        float degd = (float)wsI[DEG_OFF + d];
        float coef = (1.0f / sqrtf(fmaxf(degs, 1e-5f))) * (1.0f / sqrtf(fmaxf(degd, 1e-5f)));
        float xs[D], xd[D];
        load16(x, (long long)s * D, 1, xs);
        load16(x, (long long)d * D, 1, xd);
        float ms[D], md[D];
        edge_math_v4(sW1f, sW2tf, sb1, sb2, xs, xd, coef, ms, md);
        int slot_s = atomicAdd(&wsI[CUR_OFF + s], 1);
        float4* m0 = (float4*)(msg + (long long)slot_s * D);
        m0[0] = make_float4(ms[0], ms[1], ms[2], ms[3]);
        m0[1] = make_float4(ms[4], ms[5], ms[6], ms[7]);
        m0[2] = make_float4(ms[8], ms[9], ms[10], ms[11]);
        m0[3] = make_float4(ms[12], ms[13], ms[14], ms[15]);
        int slot_d = atomicAdd(&wsI[CUR_OFF + d], 1);
        float4* m1 = (float4*)(msg + (long long)slot_d * D);
        m1[0] = make_float4(md[0], md[1], md[2], md[3]);
        m1[1] = make_float4(md[4], md[5], md[6], md[7]);
        m1[2] = make_float4(md[8], md[9], md[10], md[11]);
        m1[3] = make_float4(md[12], md[13], md[14], md[15]);
        return;
    }

    // ---------------- bf16 MFMA path ----------------
    const int wave = t >> 6;
    const int lane = t & 63;
    const int g4 = lane >> 4;      // k-oct / row-quad selector
    const int c  = lane & 15;      // column within 16-wide tile
    const int ebase = blockIdx.x * 256 + wave * 64;   // N_EDGES % 64 == 0
    if (ebase >= N_EDGES) return;

    char* wbase = smem + wave * WAVE_LDS;
    _Float16* hw = (_Float16*)wbase;                    // [16][HSTRIDE] f16
    float* vbuf = (float*)(wbase + WAVE_H_BYTES);       // [64][VSTRIDE] f32

    const ushort_t* xb  = (const ushort_t*)x;
    const ushort_t* W1b = (const ushort_t*)W1;
    const ushort_t* W2b = (const ushort_t*)W2;
    const ushort_t* b1b = (const ushort_t*)b1;
    const ushort_t* b2b = (const ushort_t*)b2;

    // B-fragments, built once per wave (L2-hot, 16B loads).
    // B1[t]: lane holds W1^T[k = g4*8+u][col = 16t+c] = W1[16t+c][g4*8+u]
    // B1s[t]: same with K-halves swapped -> implements the [xd|xs] tile.
    bf16x8_t B1[4], B1s[4];
#pragma unroll
    for (int tt = 0; tt < 4; tt++) {
        B1[tt]  = *(const bf16x8_t*)(W1b + (16 * tt + c) * (2 * D) + g4 * 8);
        B1s[tt] = *(const bf16x8_t*)(W1b + (16 * tt + c) * (2 * D) + ((g4 ^ 2) * 8));
    }
    // B2[q]: lane holds W2^T[k = q*32 + g4*8+u][col = c] = W2[c][q*32+g4*8+u] (f16)
    f16x8_t B2[2];
#pragma unroll
    for (int q = 0; q < 2; q++) {
        const ushort_t* p = W2b + c * HID + q * 32 + g4 * 8;
        uint4 raw = *(const uint4*)p;
        unsigned u[4] = {raw.x, raw.y, raw.z, raw.w};
        f16x8_t hv;
#pragma unroll
        for (int k = 0; k < 4; k++) {
            hv[2 * k]     = (_Float16)lo_bf(u[k]);
            hv[2 * k + 1] = (_Float16)hi_bf(u[k]);
        }
        B2[q] = hv;
    }
    float b1c[4];
#pragma unroll
    for (int tt = 0; tt < 4; tt++) b1c[tt] = bf_bits(b1b[16 * tt + c]);
    float b2c = bf_bits(b2b[c]);

#pragma unroll 1
    for (int G = 0; G < 4; G++) {
        const int e0 = ebase + G * 16;
        // lanes 0-15 hold s[e0+lane], lanes 16-31 hold d[e0+lane-16]
        int nid = 0;
        if (lane < 32) {
            int idx = (lane < 16) ? (e0 + lane) : (N_EDGES + e0 + lane - 16);
            nid = i64 ? (int)((const long long*)ei)[idx] : ((const int*)ei)[idx];
        }
        // A1 frag: lane l -> row = c, k = g4*8+u ; k<16 -> xs, k>=16 -> xd
        int an = __shfl(nid, (g4 < 2) ? c : (c + 16), 64);
        bf16x8_t A1 = *(const bf16x8_t*)(xb + (long long)an * D + (g4 & 1) * 8);

        // GEMM1: both orientations share the A-frag.
        f32x4_t cs[4], cd[4];
#pragma unroll
        for (int tt = 0; tt < 4; tt++) {
            f32x4_t bi = {b1c[tt], b1c[tt], b1c[tt], b1c[tt]};
            cs[tt] = __builtin_amdgcn_mfma_f32_16x16x32_bf16(A1, B1[tt],  bi, 0, 0, 0);
            cd[tt] = __builtin_amdgcn_mfma_f32_16x16x32_bf16(A1, B1s[tt], bi, 0, 0, 0);
        }

        // --- S tile: relu(h) -> f16 LDS -> GEMM2 ---
#pragma unroll
        for (int tt = 0; tt < 4; tt++)
#pragma unroll
            for (int r = 0; r < 4; r++)
                hw[(g4 * 4 + r) * HSTRIDE + 16 * tt + c] = (_Float16)fmaxf(cs[tt][r], 0.0f);
        f32x4_t vS = {b2c, b2c, b2c, b2c};
#pragma unroll
        for (int q = 0; q < 2; q++) {
            f16x8_t a2 = *(const f16x8_t*)(hw + c * HSTRIDE + q * 32 + g4 * 8);
            vS = __builtin_amdgcn_mfma_f32_16x16x32_f16(a2, B2[q], vS, 0, 0, 0);
        }
#pragma unroll
        for (int r = 0; r < 4; r++)
            vbuf[(G * 16 + g4 * 4 + r) * VSTRIDE + c] = vS[r];

        // --- D tile (reuses h buffer; same-wave DS ordering makes this safe) ---
#pragma unroll
        for (int tt = 0; tt < 4; tt++)
#pragma unroll
            for (int r = 0; r < 4; r++)
                hw[(g4 * 4 + r) * HSTRIDE + 16 * tt + c] = (_Float16)fmaxf(cd[tt][r], 0.0f);
        f32x4_t vD = {b2c, b2c, b2c, b2c};
#pragma unroll
        for (int q = 0; q < 2; q++) {
            f16x8_t a2 = *(const f16x8_t*)(hw + c * HSTRIDE + q * 32 + g4 * 8);
            vD = __builtin_amdgcn_mfma_f32_16x16x32_f16(a2, B2[q], vD, 0, 0, 0);
        }
#pragma unroll
        for (int r = 0; r < 4; r++)
            vbuf[(G * 16 + g4 * 4 + r) * VSTRIDE + 16 + c] = vD[r];
    }

    // ---------------- epilogue: thread-per-edge ----------------
    int e = ebase + lane;
    int s, d;
    load_edge(ei, e, i64, s, d);
    float degs = (float)wsI[DEG_OFF + s];
    float degd = (float)wsI[DEG_OFF + d];
    float coef = (1.0f / sqrtf(fmaxf(degs, 1e-5f))) * (1.0f / sqrtf(fmaxf(degd, 1e-5f)));

    float vs[D], vd[D];
    {
        const f32x4_t* vp = (const f32x4_t*)(vbuf + lane * VSTRIDE);
#pragma unroll
        for (int i = 0; i < 4; i++) {
            f32x4_t u = vp[i];
            vs[4 * i] = u[0]; vs[4 * i + 1] = u[1]; vs[4 * i + 2] = u[2]; vs[4 * i + 3] = u[3];
        }
        const f32x4_t* vq = (const f32x4_t*)(vbuf + lane * VSTRIDE + 16);
#pragma unroll
        for (int i = 0; i < 4; i++) {
            f32x4_t u = vq[i];
            vd[4 * i] = u[0]; vd[4 * i + 1] = u[1]; vd[4 * i + 2] = u[2]; vd[4 * i + 3] = u[3];
        }
    }
    float xs[D], xd[D];
    load16(x, (long long)s * D, 0, xs);
    load16(x, (long long)d * D, 0, xd);

    float ns = 0.0f, nd = 0.0f;
#pragma unroll
    for (int i = 0; i < D; i++) { ns = fmaf(vs[i], vs[i], ns); nd = fmaf(vd[i], vd[i], nd); }
    float is_ = 1.0f / fmaxf(sqrtf(ns), 1e-12f);
    float id_ = 1.0f / fmaxf(sqrtf(nd), 1e-12f);
#pragma unroll
    for (int i = 0; i < D; i++) { vs[i] *= is_; vd[i] *= id_; }

    float ms[D], md[D];
    float dot1 = 0.0f;
#pragma unroll
    for (int i = 0; i < D; i++) dot1 = fmaf(vd[i], xd[i], dot1);
#pragma unroll
    for (int i = 0; i < D; i++) ms[i] = fmaf(-2.0f * dot1, vd[i], xd[i]);
    float dot2 = 0.0f;
#pragma unroll
    for (int i = 0; i < D; i++) dot2 = fmaf(vs[i], ms[i], dot2);
#pragma unroll
    for (int i = 0; i < D; i++) ms[i] = coef * fmaf(-2.0f * dot2, vs[i], ms[i]);
    float dot3 = 0.0f;
#pragma unroll
    for (int i = 0; i < D; i++) dot3 = fmaf(vs[i], xs[i], dot3);
#pragma unroll
    for (int i = 0; i < D; i++) md[i] = fmaf(-2.0f * dot3, vs[i], xs[i]);
    float dot4 = 0.0f;
#pragma unroll
    for (int i = 0; i < D; i++) dot4 = fmaf(vd[i], md[i], dot4);
#pragma unroll
    for (int i = 0; i < D; i++) md[i] = coef * fmaf(-2.0f * dot4, vd[i], md[i]);

    int slot_s = atomicAdd(&wsI[CUR_OFF + s], 1);
    float4* m0 = (float4*)(msg + (long long)slot_s * D);
    m0[0] = make_float4(ms[0], ms[1], ms[2], ms[3]);
    m0[1] = make_float4(ms[4], ms[5], ms[6], ms[7]);
    m0[2] = make_float4(ms[8], ms[9], ms[10], ms[11]);
    m0[3] = make_float4(ms[12], ms[13], ms[14], ms[15]);
    int slot_d = atomicAdd(&wsI[CUR_OFF + d], 1);
    float4* m1 = (float4*)(msg + (long long)slot_d * D);
    m1[0] = make_float4(md[0], md[1], md[2], md[3]);
    m1[1] = make_float4(md[4], md[5], md[6], md[7]);
    m1[2] = make_float4(md[8], md[9], md[10], md[11]);
    m1[3] = make_float4(md[12], md[13], md[14], md[15]);
}

// Gather: 4 lanes per node (lane c -> dims 4c..4c+3), unroll-2 accumulation.
__global__ __launch_bounds__(256) void csr_gather_kernel(
    const void* __restrict__ x,
    const void* __restrict__ ei,
    const int* __restrict__ wsI,
    void* __restrict__ out)
{
    __shared__ int sfl[2];
    if (threadIdx.x == 0) detect_flags(x, ei, sfl);
    __syncthreads();
    int f32 = sfl[0];

    int n = blockIdx.x * 64 + (threadIdx.x >> 2);
    int c = threadIdx.x & 3;
    if (n >= N_NODES) return;

    const int* off = wsI + OFF_OFF;
    const float4* msg4 = (const float4*)(wsI + MSG_OFF_I);

    int beg = off[n], end = off[n + 1];
    float4 a = make_float4(0.0f, 0.0f, 0.0f, 0.0f);
    int it = beg;
    for (; it + 2 <= end; it += 2) {
        float4 u = msg4[(long long)it * 4 + c];
        float4 v = msg4[(long long)(it + 1) * 4 + c];
        a.x += u.x + v.x; a.y += u.y + v.y; a.z += u.z + v.z; a.w += u.w + v.w;
    }
    if (it < end) {
        float4 u = msg4[(long long)it * 4 + c];
        a.x += u.x; a.y += u.y; a.z += u.z; a.w += u.w;
    }

    long long xb = (long long)n * D + 4 * c;
    float4 xv;
    if (f32) {
        xv = *(const float4*)((const float*)x + xb);
    } else {
        uint2 u = *(const uint2*)((const ushort_t*)x + xb);
        xv.x = lo_bf(u.x); xv.y = hi_bf(u.x);
        xv.z = lo_bf(u.y); xv.w = hi_bf(u.y);
    }
    float4 r;
    r.x = fmaxf(xv.x + a.x, 0.0f);
    r.y = fmaxf(xv.y + a.y, 0.0f);
    r.z = fmaxf(xv.z + a.z, 0.0f);
    r.w = fmaxf(xv.w + a.w, 0.0f);
    if (f32) {
        *(float4*)((float*)out + xb) = r;
    } else {
        uint2 o;
        o.x = (unsigned)f2bf(r.x) | ((unsigned)f2bf(r.y) << 16);
        o.y = (unsigned)f2bf(r.z) | ((unsigned)f2bf(r.w) << 16);
        *(uint2*)((ushort_t*)out + xb) = o;
    }
}

// ===========================================================================
// Fallback path (known-good): float atomics into acc
// ===========================================================================
__global__ void fb_init_kernel(float* __restrict__ ws,
                               const void* __restrict__ x,
                               const void* __restrict__ ei) {
    int i = blockIdx.x * blockDim.x + threadIdx.x;
    if (i < FB_FLAGS) ws[i] = 0.0f;
    if (blockIdx.x == 0 && threadIdx.x == 0)
        detect_flags(x, ei, (int*)(ws + FB_FLAGS));
}

__global__ void fb_deg_kernel(const void* __restrict__ ei, float* __restrict__ ws) {
    int i64 = ((const int*)(ws + FB_FLAGS))[1];
    int e = blockIdx.x * blockDim.x + threadIdx.x;
    if (e >= N_EDGES) return;
    int s, d;
    load_edge(ei, e, i64, s, d);
    atomicAdd(&ws[s], 1.0f);
    atomicAdd(&ws[d], 1.0f);
}

__global__ __launch_bounds__(256) void fb_edge_kernel(
    const void* __restrict__ x, const void* __restrict__ ei,
    const void* __restrict__ W1, const void* __restrict__ b1,
    const void* __restrict__ W2, const void* __restrict__ b2,
    float* __restrict__ ws)
{
    __shared__ __align__(16) float sW1[HID * 2 * D];
    __shared__ __align__(16) float sW2t[HID * D];
    __shared__ float sb1[HID];
    __shared__ float sb2[D];
    const int* flags = (const int*)(ws + FB_FLAGS);
    int f32 = flags[0], i64 = flags[1];
    stage_weights(W1, b1, W2, b2, f32, sW1, sW2t, sb1, sb2);
    __syncthreads();
    int e = blockIdx.x * blockDim.x + threadIdx.x;
    if (e >= N_EDGES) return;
    int s, d;
    load_edge(ei, e, i64, s, d);
    float xs[D], xd[D];
    load16(x, (long long)s * D, f32, xs);
    load16(x, (long long)d * D, f32, xd);
    float coef = (1.0f / sqrtf(fmaxf(ws[s], 1e-5f))) * (1.0f / sqrtf(fmaxf(ws[d], 1e-5f)));
    float ms[D], md[D];
    edge_math_v4(sW1, sW2t, sb1, sb2, xs, xd, coef, ms, md);
    float* acc = ws + FB_NDEG;
#pragma unroll
    for (int i = 0; i < D; i++) atomicAdd(&acc[(long long)s * D + i], ms[i]);
#pragma unroll
    for (int i = 0; i < D; i++) atomicAdd(&acc[(long long)d * D + i], md[i]);
}

__global__ void fb_finalize_kernel(const void* __restrict__ x,
                                   const float* __restrict__ ws,
                                   void* __restrict__ out)
{
    int f32 = ((const int*)(ws + FB_FLAGS))[0];
    const float* acc = ws + FB_NDEG;
    int i = blockIdx.x * blockDim.x + threadIdx.x;
    if (i >= FB_NACC) return;
    float v = ld_f(x, i, f32) + acc[i];
    v = fmaxf(v, 0.0f);
    if (f32) ((float*)out)[i] = v;
    else     ((__hip_bfloat16*)out)[i] = __float2bfloat16(v);
}

// ===========================================================================
extern "C" void kernel_launch(void* const* d_in, const int* in_sizes, int n_in,
                              void* d_out, int out_size, void* d_ws, size_t ws_size,
                              hipStream_t stream)
{
    const void* x  = d_in[0];
    const void* ei = d_in[1];
    const void* W1 = d_in[2];
    const void* b1 = d_in[3];
    const void* W2 = d_in[4];
    const void* b2 = d_in[5];

    int blk = 256;
    if (ws_size >= CSR_NEEDED_BYTES) {
        int* wsI = (int*)d_ws;
        hipMemsetAsync(d_ws, 0, (size_t)4 * N_NODES * sizeof(int), stream);
        csr_count_kernel<<<(N_EDGES + blk - 1) / blk, blk, 0, stream>>>(ei, x, wsI);
        csr_scan1_kernel<<<SCAN_G, SCAN_B, 0, stream>>>(wsI);
        csr_scan3_kernel<<<SCAN_G, SCAN_B, 0, stream>>>(wsI);
        csr_edge_kernel<<<(N_EDGES + blk - 1) / blk, blk, 0, stream>>>(x, ei, W1, b1, W2, b2, wsI);
        csr_gather_kernel<<<(N_NODES + 63) / 64, blk, 0, stream>>>(x, ei, wsI, d_out);
    } else {
        float* ws = (float*)d_ws;
        fb_init_kernel<<<(FB_FLAGS + blk - 1) / blk, blk, 0, stream>>>(ws, x, ei);
        fb_deg_kernel<<<(N_EDGES + blk - 1) / blk, blk, 0, stream>>>(ei, ws);
        fb_edge_kernel<<<(N_EDGES + blk - 1) / blk, blk, 0, stream>>>(x, ei, W1, b1, W2, b2, ws);
        fb_finalize_kernel<<<(FB_NACC + blk - 1) / blk, blk, 0, stream>>>(x, ws, d_out);
    }
}

// Round 2
// 205.938 us; speedup vs baseline: 1.0722x; 1.0722x over previous
//
#include <hip/hip_runtime.h>
#include <hip/hip_bf16.h>
#include <hip/hip_fp16.h>

#define N_NODES 50000
#define N_EDGES 400000
#define D 16
#define HID 64

#define SCAN_B 256
#define SCAN_G ((N_NODES + SCAN_B - 1) / SCAN_B)   // 196

typedef unsigned short ushort_t;
typedef _Float16 h16x2 __attribute__((ext_vector_type(2)));

// ---------------- int-indexed workspace layout (CSR path) ----------------
#define CNT4_OFF  0                       // [4][N] replicated counts (memset to 0)
#define DEG_OFF   (4 * N_NODES)           // [N] total degree
#define OFF_OFF   (5 * N_NODES)           // [N+1] CSR offsets
#define CUR_OFF   (6 * N_NODES + 1)       // [N] claim cursors
#define BS_OFF    (7 * N_NODES + 1)       // [SCAN_G] block sums
#define MSG_OFF_I (((BS_OFF + SCAN_G) + 3) & ~3)  // [2E*16] fp32 msgs
// packed-f16 weight table: 32 jj-blocks x 52 dwords
//   [0..15]  W1 row 2jj   as f16 pairs along k
//   [16..31] W1 row 2jj+1 as f16 pairs along k
//   [32..47] W2 pairs: dword i = pack(W2[i][2jj], W2[i][2jj+1])
//   [48]     b1[2jj] (f32 bits)   [49] b1[2jj+1]   [50..51] pad
// then 16 dwords of b2 (f32 bits)
#define PREP_OFF  (MSG_OFF_I + 2 * N_EDGES * D)
#define PREP_DW   (32 * 52 + 16)
#define CSR_NEEDED_BYTES ((size_t)(PREP_OFF + PREP_DW) * 4 + 64)

// ---------------- fallback (atomic) layout ----------------
#define FB_NDEG   (N_NODES)
#define FB_NACC   (N_NODES * D)
#define FB_FLAGS  (FB_NDEG + FB_NACC)

// ---------------------------------------------------------------------------
// dtype helpers
// ---------------------------------------------------------------------------
__device__ __forceinline__ float bf_bits(ushort_t us) {
    return __uint_as_float(((unsigned)us) << 16);
}
__device__ __forceinline__ float lo_bf(unsigned u) { return __uint_as_float(u << 16); }
__device__ __forceinline__ float hi_bf(unsigned u) { return __uint_as_float(u & 0xffff0000u); }
__device__ __forceinline__ ushort_t f2bf(float v) {
    unsigned u = __float_as_uint(v);
    unsigned r = (u + 0x7fffu + ((u >> 16) & 1u)) >> 16;
    return (ushort_t)r;
}
__device__ __forceinline__ float ld_f(const void* p, int idx, int f32) {
    return f32 ? ((const float*)p)[idx]
               : bf_bits(((const ushort_t*)p)[idx]);
}

// pack two f32 into one f16x2 dword (RTZ — matches the proven kernel's numerics)
__device__ __forceinline__ unsigned pack_h2(float a, float b) {
#if __has_builtin(__builtin_amdgcn_cvt_pkrtz)
    return __builtin_bit_cast(unsigned, __builtin_amdgcn_cvt_pkrtz(a, b));
#else
    h16x2 h;
    h.x = (_Float16)a;
    h.y = (_Float16)b;
    return __builtin_bit_cast(unsigned, h);
#endif
}

// f16x2 dot with f32 accumulate: v_dot2_f32_f16 (2 MACs/instr)
#if __has_builtin(__builtin_amdgcn_fdot2)
__device__ __forceinline__ float fdot2u(unsigned a, unsigned b, float c) {
    return __builtin_amdgcn_fdot2(__builtin_bit_cast(h16x2, a),
                                  __builtin_bit_cast(h16x2, b), c, false);
}
#else
__device__ __forceinline__ float fdot2u(unsigned a, unsigned b, float c) {
    h16x2 ha = __builtin_bit_cast(h16x2, a);
    h16x2 hb = __builtin_bit_cast(h16x2, b);
    return fmaf((float)ha.x, (float)hb.x, fmaf((float)ha.y, (float)hb.y, c));
}
#endif

__device__ __forceinline__ void load16(const void* __restrict__ p, long long base,
                                       int f32, float* o) {
    if (f32) {
        const float4* q = (const float4*)((const float*)p + base);
        float4 a = q[0], b = q[1], c = q[2], d = q[3];
        o[0]=a.x; o[1]=a.y; o[2]=a.z; o[3]=a.w;
        o[4]=b.x; o[5]=b.y; o[6]=b.z; o[7]=b.w;
        o[8]=c.x; o[9]=c.y; o[10]=c.z; o[11]=c.w;
        o[12]=d.x; o[13]=d.y; o[14]=d.z; o[15]=d.w;
    } else {
        const uint4* q = (const uint4*)((const ushort_t*)p + base);
        uint4 a = q[0], b = q[1];
        unsigned u[8] = {a.x, a.y, a.z, a.w, b.x, b.y, b.z, b.w};
#pragma unroll
        for (int k = 0; k < 8; k++) {
            o[2 * k]     = lo_bf(u[k]);
            o[2 * k + 1] = hi_bf(u[k]);
        }
    }
}

__device__ __forceinline__ void load_edge(const void* __restrict__ ei, int e, int is64,
                                          int& s, int& d) {
    if (is64) {
        const long long* p = (const long long*)ei;
        s = (int)p[e];
        d = (int)p[N_EDGES + e];
    } else {
        const int* p = (const int*)ei;
        s = p[e];
        d = p[N_EDGES + e];
    }
}

__device__ __forceinline__ void detect_flags(const void* x, const void* ei, int* flags) {
    const ushort_t* h = (const ushort_t*)x;
    int f32 = 0;
    for (int k = 0; k < 256; k++) {
        float v = bf_bits(h[k]);
        if (!(v == v) || fabsf(v) > 1.0e6f) { f32 = 1; break; }
    }
    const long long* p = (const long long*)ei;
    int i64 = 1;
    for (int k = 0; k < 16; k++) {
        long long v = p[k];
        if (v < 0 || v >= N_NODES) { i64 = 0; break; }
    }
    flags[0] = f32;
    flags[1] = i64;
}

__device__ __forceinline__ void stage_weights(
    const void* W1, const void* b1, const void* W2, const void* b2, int f32,
    float* sW1, float* sW2t, float* sb1, float* sb2)
{
    int t = threadIdx.x;
    for (int idx = t; idx < HID * 2 * D; idx += blockDim.x)
        sW1[idx] = ld_f(W1, idx, f32);
    for (int idx = t; idx < HID * D; idx += blockDim.x) {
        int j = idx / D, i = idx % D;
        sW2t[idx] = ld_f(W2, i * HID + j, f32);
    }
    if (t < HID) sb1[t] = ld_f(b1, t, f32);
    if (t < D)  sb2[t] = ld_f(b2, t, f32);
}

// ---------------------------------------------------------------------------
// Full-MLP per-edge math, f32 (safety + fallback paths)
// ---------------------------------------------------------------------------
__device__ __forceinline__ void edge_math_v4(
    const float* __restrict__ sW1, const float* __restrict__ sW2t,
    const float* __restrict__ sb1, const float* __restrict__ sb2,
    const float* xs, const float* xd, float coef,
    float* ms, float* md)
{
    float vs[D], vd[D];
#pragma unroll
    for (int i = 0; i < D; i++) { vs[i] = sb2[i]; vd[i] = sb2[i]; }
#pragma unroll 4
    for (int j = 0; j < HID; j++) {
        float hs = sb1[j], hd = sb1[j];
        const float4* w4 = (const float4*)&sW1[j * 2 * D];
#pragma unroll
        for (int t = 0; t < 4; t++) {
            float4 wv = w4[t];
            int k = 4 * t;
            hs = fmaf(wv.x, xs[k],     hs); hd = fmaf(wv.x, xd[k],     hd);
            hs = fmaf(wv.y, xs[k + 1], hs); hd = fmaf(wv.y, xd[k + 1], hd);
            hs = fmaf(wv.z, xs[k + 2], hs); hd = fmaf(wv.z, xd[k + 2], hd);
            hs = fmaf(wv.w, xs[k + 3], hs); hd = fmaf(wv.w, xd[k + 3], hd);
        }
#pragma unroll
        for (int t = 0; t < 4; t++) {
            float4 wv = w4[4 + t];
            int k = 4 * t;
            hs = fmaf(wv.x, xd[k],     hs); hd = fmaf(wv.x, xs[k],     hd);
            hs = fmaf(wv.y, xd[k + 1], hs); hd = fmaf(wv.y, xs[k + 1], hd);
            hs = fmaf(wv.z, xd[k + 2], hs); hd = fmaf(wv.z, xs[k + 2], hd);
            hs = fmaf(wv.w, xd[k + 3], hs); hd = fmaf(wv.w, xs[k + 3], hd);
        }
        hs = fmaxf(hs, 0.0f);
        hd = fmaxf(hd, 0.0f);
        const float4* w24 = (const float4*)&sW2t[j * D];
#pragma unroll
        for (int t = 0; t < 4; t++) {
            float4 u = w24[t];
            int i = 4 * t;
            vs[i]     = fmaf(u.x, hs, vs[i]);     vd[i]     = fmaf(u.x, hd, vd[i]);
            vs[i + 1] = fmaf(u.y, hs, vs[i + 1]); vd[i + 1] = fmaf(u.y, hd, vd[i + 1]);
            vs[i + 2] = fmaf(u.z, hs, vs[i + 2]); vd[i + 2] = fmaf(u.z, hd, vd[i + 2]);
            vs[i + 3] = fmaf(u.w, hs, vs[i + 3]); vd[i + 3] = fmaf(u.w, hd, vd[i + 3]);
        }
    }
    float ns = 0.0f, nd = 0.0f;
#pragma unroll
    for (int i = 0; i < D; i++) { ns = fmaf(vs[i], vs[i], ns); nd = fmaf(vd[i], vd[i], nd); }
    float is_ = 1.0f / fmaxf(sqrtf(ns), 1e-12f);
    float id_ = 1.0f / fmaxf(sqrtf(nd), 1e-12f);
#pragma unroll
    for (int i = 0; i < D; i++) { vs[i] *= is_; vd[i] *= id_; }
    float dot1 = 0.0f;
#pragma unroll
    for (int i = 0; i < D; i++) dot1 = fmaf(vd[i], xd[i], dot1);
#pragma unroll
    for (int i = 0; i < D; i++) ms[i] = fmaf(-2.0f * dot1, vd[i], xd[i]);
    float dot2 = 0.0f;
#pragma unroll
    for (int i = 0; i < D; i++) dot2 = fmaf(vs[i], ms[i], dot2);
#pragma unroll
    for (int i = 0; i < D; i++) ms[i] = coef * fmaf(-2.0f * dot2, vs[i], ms[i]);
    float dot3 = 0.0f;
#pragma unroll
    for (int i = 0; i < D; i++) dot3 = fmaf(vs[i], xs[i], dot3);
#pragma unroll
    for (int i = 0; i < D; i++) md[i] = fmaf(-2.0f * dot3, vs[i], xs[i]);
    float dot4 = 0.0f;
#pragma unroll
    for (int i = 0; i < D; i++) dot4 = fmaf(vd[i], md[i], dot4);
#pragma unroll
    for (int i = 0; i < D; i++) md[i] = coef * fmaf(-2.0f * dot4, vd[i], md[i]);
}

// ===========================================================================
// CSR path kernels
// ===========================================================================
// Counting + (block 0 only) packing the f16 weight table into ws.
__global__ void csr_count_kernel(const void* __restrict__ ei,
                                 const void* __restrict__ x,
                                 const void* __restrict__ W1,
                                 const void* __restrict__ b1,
                                 const void* __restrict__ W2,
                                 const void* __restrict__ b2,
                                 int* __restrict__ wsI) {
    __shared__ int sfl[2];
    if (threadIdx.x == 0) detect_flags(x, ei, sfl);
    __syncthreads();
    int i64 = sfl[1];

    if (blockIdx.x == 0) {
        // pack weight table (bf16 interpretation; unused by the f32 path)
        unsigned* pp = (unsigned*)(wsI + PREP_OFF);
        const ushort_t* W1b = (const ushort_t*)W1;
        const ushort_t* W2b = (const ushort_t*)W2;
        const ushort_t* b1b = (const ushort_t*)b1;
        const ushort_t* b2b = (const ushort_t*)b2;
        for (int idx = threadIdx.x; idx < 32 * 52; idx += 256) {
            int jj = idx / 52, w = idx % 52;
            unsigned val = 0;
            if (w < 32) {
                int row = 2 * jj + (w >> 4), k2 = w & 15;
                val = pack_h2(bf_bits(W1b[row * 32 + 2 * k2]),
                              bf_bits(W1b[row * 32 + 2 * k2 + 1]));
            } else if (w < 48) {
                int i = w - 32;
                val = pack_h2(bf_bits(W2b[i * HID + 2 * jj]),
                              bf_bits(W2b[i * HID + 2 * jj + 1]));
            } else if (w == 48) {
                val = __float_as_uint(bf_bits(b1b[2 * jj]));
            } else if (w == 49) {
                val = __float_as_uint(bf_bits(b1b[2 * jj + 1]));
            }
            pp[idx] = val;
        }
        if (threadIdx.x < D)
            pp[32 * 52 + threadIdx.x] = __float_as_uint(bf_bits(b2b[threadIdx.x]));
    }

    int e = blockIdx.x * blockDim.x + threadIdx.x;
    if (e >= N_EDGES) return;
    int s, d;
    load_edge(ei, e, i64, s, d);
    int r = (e & 3) * N_NODES;
    atomicAdd(&wsI[CNT4_OFF + r + s], 1);
    atomicAdd(&wsI[CNT4_OFF + r + d], 1);
}

__global__ __launch_bounds__(SCAN_B) void csr_scan1_kernel(int* __restrict__ wsI) {
    __shared__ int sm[SCAN_B];
    int t = threadIdx.x;
    int g = blockIdx.x * SCAN_B + t;
    int c = 0;
    if (g < N_NODES) {
        c = wsI[CNT4_OFF + g] + wsI[CNT4_OFF + N_NODES + g]
          + wsI[CNT4_OFF + 2 * N_NODES + g] + wsI[CNT4_OFF + 3 * N_NODES + g];
        wsI[DEG_OFF + g] = c;
    }
    sm[t] = c;
    __syncthreads();
    for (int st = SCAN_B / 2; st > 0; st >>= 1) {
        if (t < st) sm[t] += sm[t + st];
        __syncthreads();
    }
    if (t == 0) wsI[BS_OFF + blockIdx.x] = sm[0];
}

__global__ __launch_bounds__(SCAN_B) void csr_scan3_kernel(int* __restrict__ wsI) {
    __shared__ int sB[SCAN_B];
    __shared__ int sm[SCAN_B];
    int t = threadIdx.x;
    int bsv = (t < SCAN_G) ? wsI[BS_OFF + t] : 0;
    sB[t] = bsv;
    __syncthreads();
    for (int st = 1; st < SCAN_B; st <<= 1) {
        int u = (t >= st) ? sB[t - st] : 0;
        __syncthreads();
        sB[t] += u;
        __syncthreads();
    }
    int blockBase = sB[blockIdx.x] - wsI[BS_OFF + blockIdx.x];

    int g = blockIdx.x * SCAN_B + t;
    int c = (g < N_NODES) ? wsI[DEG_OFF + g] : 0;
    sm[t] = c;
    __syncthreads();
    for (int st = 1; st < SCAN_B; st <<= 1) {
        int u = (t >= st) ? sm[t - st] : 0;
        __syncthreads();
        sm[t] += u;
        __syncthreads();
    }
    int excl = sm[t] - c + blockBase;
    if (g < N_NODES) {
        wsI[OFF_OFF + g] = excl;
        wsI[CUR_OFF + g] = excl;
        if (g == N_NODES - 1) wsI[OFF_OFF + N_NODES] = excl + c;
    }
}

// ---------------------------------------------------------------------------
// Edge kernel. bf16 path: weights come from the pre-packed f16 table via a
// separate const __restrict__ pointer with loop-uniform addresses -> the
// compiler emits s_load into SGPRs. v_dot2_f32_f16 takes the weight operand
// from SGPR directly (1 scalar src allowed), so the main loop touches the
// LDS pipe ZERO times (old kernel: 384 ds_read_b128 per lane-edge = the
// ~47 us/CU LDS-pipe bound). Numerics bitwise-identical to the proven
// 200 us kernel (same RTZ packing, same op order).
// ---------------------------------------------------------------------------
__global__ __launch_bounds__(256) void csr_edge_kernel(
    const void* __restrict__ x,
    const void* __restrict__ ei,
    const void* __restrict__ W1,
    const void* __restrict__ b1,
    const void* __restrict__ W2,
    const void* __restrict__ b2,
    const unsigned* __restrict__ prep,
    int* __restrict__ wsI)
{
    __shared__ __align__(16) float sW1f[HID * 2 * D];   // f32 path only
    __shared__ __align__(16) float sW2tf[HID * D];      // f32 path only
    __shared__ float sb1[HID];
    __shared__ float sb2[D];
    __shared__ int sfl[2];

    if (threadIdx.x == 0) detect_flags(x, ei, sfl);
    __syncthreads();
    int f32 = sfl[0], i64 = sfl[1];
    int t = threadIdx.x;

    if (f32) {
        for (int idx = t; idx < HID * 2 * D; idx += 256)
            sW1f[idx] = ld_f(W1, idx, 1);
        for (int idx = t; idx < HID * D; idx += 256) {
            int j = idx / D, i = idx % D;
            sW2tf[idx] = ld_f(W2, i * HID + j, 1);
        }
        if (t < HID) sb1[t] = ld_f(b1, t, 1);
        if (t < D)  sb2[t] = ld_f(b2, t, 1);
        __syncthreads();
    }

    int e = blockIdx.x * 256 + t;
    if (e >= N_EDGES) return;

    int s, d;
    load_edge(ei, e, i64, s, d);
    float degs = (float)wsI[DEG_OFF + s];
    float degd = (float)wsI[DEG_OFF + d];
    float coef = (1.0f / sqrtf(fmaxf(degs, 1e-5f))) * (1.0f / sqrtf(fmaxf(degd, 1e-5f)));
    float* msg = (float*)(wsI + MSG_OFF_I);

    if (!f32) {
        // x rows as f16 pairs (bf16 -> f16 exact)
        unsigned xsh[8], xdh[8];
        {
            const uint4* q = (const uint4*)((const ushort_t*)x + (long long)s * D);
            uint4 a = q[0], b = q[1];
            unsigned u[8] = {a.x, a.y, a.z, a.w, b.x, b.y, b.z, b.w};
#pragma unroll
            for (int k = 0; k < 8; k++) xsh[k] = pack_h2(lo_bf(u[k]), hi_bf(u[k]));
        }
        {
            const uint4* q = (const uint4*)((const ushort_t*)x + (long long)d * D);
            uint4 a = q[0], b = q[1];
            unsigned u[8] = {a.x, a.y, a.z, a.w, b.x, b.y, b.z, b.w};
#pragma unroll
            for (int k = 0; k < 8; k++) xdh[k] = pack_h2(lo_bf(u[k]), hi_bf(u[k]));
        }

        const float* b2f = (const float*)(prep + 32 * 52);
        float vs[D], vd[D];
#pragma unroll
        for (int i = 0; i < D; i++) { vs[i] = b2f[i]; vd[i] = b2f[i]; }

#pragma unroll 1
        for (int jj = 0; jj < 32; jj++) {
            const uint4* wb = (const uint4*)(prep + jj * 52);   // uniform -> s_load
            uint4 q0 = wb[0], q1 = wb[1], q2 = wb[2], q3 = wb[3];     // W1 row 2jj
            uint4 q4 = wb[4], q5 = wb[5], q6 = wb[6], q7 = wb[7];     // W1 row 2jj+1
            uint4 q8 = wb[8], q9 = wb[9], qA = wb[10], qB = wb[11];   // W2 pairs
            const float* bb = (const float*)(prep + jj * 52 + 48);
            float hs0 = bb[0], hd0 = bb[0];
            float hs1 = bb[1], hd1 = bb[1];

            unsigned r0[16] = {q0.x, q0.y, q0.z, q0.w, q1.x, q1.y, q1.z, q1.w,
                               q2.x, q2.y, q2.z, q2.w, q3.x, q3.y, q3.z, q3.w};
            unsigned r1[16] = {q4.x, q4.y, q4.z, q4.w, q5.x, q5.y, q5.z, q5.w,
                               q6.x, q6.y, q6.z, q6.w, q7.x, q7.y, q7.z, q7.w};
            unsigned w2a[16] = {q8.x, q8.y, q8.z, q8.w, q9.x, q9.y, q9.z, q9.w,
                                qA.x, qA.y, qA.z, qA.w, qB.x, qB.y, qB.z, qB.w};
#pragma unroll
            for (int k = 0; k < 8; k++) {        // k-pairs 0..7: [xs | .] part
                hs0 = fdot2u(r0[k], xsh[k], hs0);
                hd0 = fdot2u(r0[k], xdh[k], hd0);
                hs1 = fdot2u(r1[k], xsh[k], hs1);
                hd1 = fdot2u(r1[k], xdh[k], hd1);
            }
#pragma unroll
            for (int k = 0; k < 8; k++) {        // k-pairs 8..15: [. | xd] part
                hs0 = fdot2u(r0[8 + k], xdh[k], hs0);
                hd0 = fdot2u(r0[8 + k], xsh[k], hd0);
                hs1 = fdot2u(r1[8 + k], xdh[k], hs1);
                hd1 = fdot2u(r1[8 + k], xsh[k], hd1);
            }
            hs0 = fmaxf(hs0, 0.0f); hd0 = fmaxf(hd0, 0.0f);
            hs1 = fmaxf(hs1, 0.0f); hd1 = fmaxf(hd1, 0.0f);
            unsigned hsp = pack_h2(hs0, hs1);
            unsigned hdp = pack_h2(hd0, hd1);
#pragma unroll
            for (int i = 0; i < D; i++) {
                vs[i] = fdot2u(w2a[i], hsp, vs[i]);
                vd[i] = fdot2u(w2a[i], hdp, vd[i]);
            }
        }

        // epilogue (f32): recover xs/xd exactly from f16 pairs
        float xs[D], xd[D];
#pragma unroll
        for (int k = 0; k < 8; k++) {
            h16x2 a = __builtin_bit_cast(h16x2, xsh[k]);
            xs[2 * k] = (float)a.x; xs[2 * k + 1] = (float)a.y;
            h16x2 b = __builtin_bit_cast(h16x2, xdh[k]);
            xd[2 * k] = (float)b.x; xd[2 * k + 1] = (float)b.y;
        }

        float ns = 0.0f, nd = 0.0f;
#pragma unroll
        for (int i = 0; i < D; i++) { ns = fmaf(vs[i], vs[i], ns); nd = fmaf(vd[i], vd[i], nd); }
        float is_ = 1.0f / fmaxf(sqrtf(ns), 1e-12f);
        float id_ = 1.0f / fmaxf(sqrtf(nd), 1e-12f);
#pragma unroll
        for (int i = 0; i < D; i++) { vs[i] *= is_; vd[i] *= id_; }

        float ms[D], md[D];
        float dot1 = 0.0f;
#pragma unroll
        for (int i = 0; i < D; i++) dot1 = fmaf(vd[i], xd[i], dot1);
#pragma unroll
        for (int i = 0; i < D; i++) ms[i] = fmaf(-2.0f * dot1, vd[i], xd[i]);
        float dot2 = 0.0f;
#pragma unroll
        for (int i = 0; i < D; i++) dot2 = fmaf(vs[i], ms[i], dot2);
#pragma unroll
        for (int i = 0; i < D; i++) ms[i] = coef * fmaf(-2.0f * dot2, vs[i], ms[i]);
        float dot3 = 0.0f;
#pragma unroll
        for (int i = 0; i < D; i++) dot3 = fmaf(vs[i], xs[i], dot3);
#pragma unroll
        for (int i = 0; i < D; i++) md[i] = fmaf(-2.0f * dot3, vs[i], xs[i]);
        float dot4 = 0.0f;
#pragma unroll
        for (int i = 0; i < D; i++) dot4 = fmaf(vd[i], md[i], dot4);
#pragma unroll
        for (int i = 0; i < D; i++) md[i] = coef * fmaf(-2.0f * dot4, vd[i], md[i]);

        int slot_s = atomicAdd(&wsI[CUR_OFF + s], 1);
        float4* m0 = (float4*)(msg + (long long)slot_s * D);
        m0[0] = make_float4(ms[0], ms[1], ms[2], ms[3]);
        m0[1] = make_float4(ms[4], ms[5], ms[6], ms[7]);
        m0[2] = make_float4(ms[8], ms[9], ms[10], ms[11]);
        m0[3] = make_float4(ms[12], ms[13], ms[14], ms[15]);
        int slot_d = atomicAdd(&wsI[CUR_OFF + d], 1);
        float4* m1 = (float4*)(msg + (long long)slot_d * D);
        m1[0] = make_float4(md[0], md[1], md[2], md[3]);
        m1[1] = make_float4(md[4], md[5], md[6], md[7]);
        m1[2] = make_float4(md[8], md[9], md[10], md[11]);
        m1[3] = make_float4(md[12], md[13], md[14], md[15]);
    } else {
        float xs[D], xd[D];
        load16(x, (long long)s * D, 1, xs);
        load16(x, (long long)d * D, 1, xd);
        float ms[D], md[D];
        edge_math_v4(sW1f, sW2tf, sb1, sb2, xs, xd, coef, ms, md);
        int slot_s = atomicAdd(&wsI[CUR_OFF + s], 1);
        float4* m0 = (float4*)(msg + (long long)slot_s * D);
        m0[0] = make_float4(ms[0], ms[1], ms[2], ms[3]);
        m0[1] = make_float4(ms[4], ms[5], ms[6], ms[7]);
        m0[2] = make_float4(ms[8], ms[9], ms[10], ms[11]);
        m0[3] = make_float4(ms[12], ms[13], ms[14], ms[15]);
        int slot_d = atomicAdd(&wsI[CUR_OFF + d], 1);
        float4* m1 = (float4*)(msg + (long long)slot_d * D);
        m1[0] = make_float4(md[0], md[1], md[2], md[3]);
        m1[1] = make_float4(md[4], md[5], md[6], md[7]);
        m1[2] = make_float4(md[8], md[9], md[10], md[11]);
        m1[3] = make_float4(md[12], md[13], md[14], md[15]);
    }
}

// Gather: 4 lanes per node (lane c -> dims 4c..4c+3), unroll-2 accumulation.
__global__ __launch_bounds__(256) void csr_gather_kernel(
    const void* __restrict__ x,
    const void* __restrict__ ei,
    const int* __restrict__ wsI,
    void* __restrict__ out)
{
    __shared__ int sfl[2];
    if (threadIdx.x == 0) detect_flags(x, ei, sfl);
    __syncthreads();
    int f32 = sfl[0];

    int n = blockIdx.x * 64 + (threadIdx.x >> 2);
    int c = threadIdx.x & 3;
    if (n >= N_NODES) return;

    const int* off = wsI + OFF_OFF;
    const float4* msg4 = (const float4*)(wsI + MSG_OFF_I);

    int beg = off[n], end = off[n + 1];
    float4 a = make_float4(0.0f, 0.0f, 0.0f, 0.0f);
    int it = beg;
    for (; it + 2 <= end; it += 2) {
        float4 u = msg4[(long long)it * 4 + c];
        float4 v = msg4[(long long)(it + 1) * 4 + c];
        a.x += u.x + v.x; a.y += u.y + v.y; a.z += u.z + v.z; a.w += u.w + v.w;
    }
    if (it < end) {
        float4 u = msg4[(long long)it * 4 + c];
        a.x += u.x; a.y += u.y; a.z += u.z; a.w += u.w;
    }

    long long xb = (long long)n * D + 4 * c;
    float4 xv;
    if (f32) {
        xv = *(const float4*)((const float*)x + xb);
    } else {
        uint2 u = *(const uint2*)((const ushort_t*)x + xb);
        xv.x = lo_bf(u.x); xv.y = hi_bf(u.x);
        xv.z = lo_bf(u.y); xv.w = hi_bf(u.y);
    }
    float4 r;
    r.x = fmaxf(xv.x + a.x, 0.0f);
    r.y = fmaxf(xv.y + a.y, 0.0f);
    r.z = fmaxf(xv.z + a.z, 0.0f);
    r.w = fmaxf(xv.w + a.w, 0.0f);
    if (f32) {
        *(float4*)((float*)out + xb) = r;
    } else {
        uint2 o;
        o.x = (unsigned)f2bf(r.x) | ((unsigned)f2bf(r.y) << 16);
        o.y = (unsigned)f2bf(r.z) | ((unsigned)f2bf(r.w) << 16);
        *(uint2*)((ushort_t*)out + xb) = o;
    }
}

// ===========================================================================
// Fallback path (known-good): float atomics into acc
// ===========================================================================
__global__ void fb_init_kernel(float* __restrict__ ws,
                               const void* __restrict__ x,
                               const void* __restrict__ ei) {
    int i = blockIdx.x * blockDim.x + threadIdx.x;
    if (i < FB_FLAGS) ws[i] = 0.0f;
    if (blockIdx.x == 0 && threadIdx.x == 0)
        detect_flags(x, ei, (int*)(ws + FB_FLAGS));
}

__global__ void fb_deg_kernel(const void* __restrict__ ei, float* __restrict__ ws) {
    int i64 = ((const int*)(ws + FB_FLAGS))[1];
    int e = blockIdx.x * blockDim.x + threadIdx.x;
    if (e >= N_EDGES) return;
    int s, d;
    load_edge(ei, e, i64, s, d);
    atomicAdd(&ws[s], 1.0f);
    atomicAdd(&ws[d], 1.0f);
}

__global__ __launch_bounds__(256) void fb_edge_kernel(
    const void* __restrict__ x, const void* __restrict__ ei,
    const void* __restrict__ W1, const void* __restrict__ b1,
    const void* __restrict__ W2, const void* __restrict__ b2,
    float* __restrict__ ws)
{
    __shared__ __align__(16) float sW1[HID * 2 * D];
    __shared__ __align__(16) float sW2t[HID * D];
    __shared__ float sb1[HID];
    __shared__ float sb2[D];
    const int* flags = (const int*)(ws + FB_FLAGS);
    int f32 = flags[0], i64 = flags[1];
    stage_weights(W1, b1, W2, b2, f32, sW1, sW2t, sb1, sb2);
    __syncthreads();
    int e = blockIdx.x * blockDim.x + threadIdx.x;
    if (e >= N_EDGES) return;
    int s, d;
    load_edge(ei, e, i64, s, d);
    float xs[D], xd[D];
    load16(x, (long long)s * D, f32, xs);
    load16(x, (long long)d * D, f32, xd);
    float coef = (1.0f / sqrtf(fmaxf(ws[s], 1e-5f))) * (1.0f / sqrtf(fmaxf(ws[d], 1e-5f)));
    float ms[D], md[D];
    edge_math_v4(sW1, sW2t, sb1, sb2, xs, xd, coef, ms, md);
    float* acc = ws + FB_NDEG;
#pragma unroll
    for (int i = 0; i < D; i++) atomicAdd(&acc[(long long)s * D + i], ms[i]);
#pragma unroll
    for (int i = 0; i < D; i++) atomicAdd(&acc[(long long)d * D + i], md[i]);
}

__global__ void fb_finalize_kernel(const void* __restrict__ x,
                                   const float* __restrict__ ws,
                                   void* __restrict__ out)
{
    int f32 = ((const int*)(ws + FB_FLAGS))[0];
    const float* acc = ws + FB_NDEG;
    int i = blockIdx.x * blockDim.x + threadIdx.x;
    if (i >= FB_NACC) return;
    float v = ld_f(x, i, f32) + acc[i];
    v = fmaxf(v, 0.0f);
    if (f32) ((float*)out)[i] = v;
    else     ((__hip_bfloat16*)out)[i] = __float2bfloat16(v);
}

// ===========================================================================
extern "C" void kernel_launch(void* const* d_in, const int* in_sizes, int n_in,
                              void* d_out, int out_size, void* d_ws, size_t ws_size,
                              hipStream_t stream)
{
    const void* x  = d_in[0];
    const void* ei = d_in[1];
    const void* W1 = d_in[2];
    const void* b1 = d_in[3];
    const void* W2 = d_in[4];
    const void* b2 = d_in[5];

    int blk = 256;
    if (ws_size >= CSR_NEEDED_BYTES) {
        int* wsI = (int*)d_ws;
        hipMemsetAsync(d_ws, 0, (size_t)4 * N_NODES * sizeof(int), stream);
        csr_count_kernel<<<(N_EDGES + blk - 1) / blk, blk, 0, stream>>>(ei, x, W1, b1, W2, b2, wsI);
        csr_scan1_kernel<<<SCAN_G, SCAN_B, 0, stream>>>(wsI);
        csr_scan3_kernel<<<SCAN_G, SCAN_B, 0, stream>>>(wsI);
        csr_edge_kernel<<<(N_EDGES + blk - 1) / blk, blk, 0, stream>>>(
            x, ei, W1, b1, W2, b2, (const unsigned*)(wsI + PREP_OFF), wsI);
        csr_gather_kernel<<<(N_NODES + 63) / 64, blk, 0, stream>>>(x, ei, wsI, d_out);
    } else {
        float* ws = (float*)d_ws;
        fb_init_kernel<<<(FB_FLAGS + blk - 1) / blk, blk, 0, stream>>>(ws, x, ei);
        fb_deg_kernel<<<(N_EDGES + blk - 1) / blk, blk, 0, stream>>>(ei, ws);
        fb_edge_kernel<<<(N_EDGES + blk - 1) / blk, blk, 0, stream>>>(x, ei, W1, b1, W2, b2, ws);
        fb_finalize_kernel<<<(FB_NACC + blk - 1) / blk, blk, 0, stream>>>(x, ws, d_out);
    }
}

// Round 3
// 204.654 us; speedup vs baseline: 1.0789x; 1.0063x over previous
//
#include <hip/hip_runtime.h>
#include <hip/hip_bf16.h>
#include <hip/hip_fp16.h>

#define N_NODES 50000
#define N_EDGES 400000
#define D 16
#define HID 64

#define SCAN_B 256
#define SCAN_G ((N_NODES + SCAN_B - 1) / SCAN_B)   // 196

typedef unsigned short ushort_t;

// ---------------- int-indexed workspace layout (CSR path) ----------------
#define CNT4_OFF  0                       // [4][N] replicated counts (memset to 0)
#define DEG_OFF   (4 * N_NODES)           // [N] total degree
#define OFF_OFF   (5 * N_NODES)           // [N+1] CSR offsets
#define CUR_OFF   (6 * N_NODES + 1)       // [N] claim cursors
#define BS_OFF    (7 * N_NODES + 1)       // [SCAN_G] block sums
#define MSG_OFF_I (((BS_OFF + SCAN_G) + 3) & ~3)  // [2E*16] fp32 msgs
// f32 weight table: 64 j-rows x 64 dwords (256B, 16B-aligned rows)
//   [0..31]  W1[j][k] f32    [32..47] W2[i][j] f32 (i=0..15)
//   [48]     b1[j]           [49..63] pad
// then 16 dwords of b2 (f32)
#define PREP_OFF  (MSG_OFF_I + 2 * N_EDGES * D)
#define PREP_DW   (64 * 64 + 16)
#define CSR_NEEDED_BYTES ((size_t)(PREP_OFF + PREP_DW) * 4 + 64)

// ---------------- fallback (atomic) layout ----------------
#define FB_NDEG   (N_NODES)
#define FB_NACC   (N_NODES * D)
#define FB_FLAGS  (FB_NDEG + FB_NACC)

// ---------------------------------------------------------------------------
// dtype helpers
// ---------------------------------------------------------------------------
__device__ __forceinline__ float bf_bits(ushort_t us) {
    return __uint_as_float(((unsigned)us) << 16);
}
__device__ __forceinline__ float lo_bf(unsigned u) { return __uint_as_float(u << 16); }
__device__ __forceinline__ float hi_bf(unsigned u) { return __uint_as_float(u & 0xffff0000u); }
__device__ __forceinline__ ushort_t f2bf(float v) {
    unsigned u = __float_as_uint(v);
    unsigned r = (u + 0x7fffu + ((u >> 16) & 1u)) >> 16;
    return (ushort_t)r;
}
__device__ __forceinline__ float ld_f(const void* p, int idx, int f32) {
    return f32 ? ((const float*)p)[idx]
               : bf_bits(((const ushort_t*)p)[idx]);
}

__device__ __forceinline__ void load16(const void* __restrict__ p, long long base,
                                       int f32, float* o) {
    if (f32) {
        const float4* q = (const float4*)((const float*)p + base);
        float4 a = q[0], b = q[1], c = q[2], d = q[3];
        o[0]=a.x; o[1]=a.y; o[2]=a.z; o[3]=a.w;
        o[4]=b.x; o[5]=b.y; o[6]=b.z; o[7]=b.w;
        o[8]=c.x; o[9]=c.y; o[10]=c.z; o[11]=c.w;
        o[12]=d.x; o[13]=d.y; o[14]=d.z; o[15]=d.w;
    } else {
        const uint4* q = (const uint4*)((const ushort_t*)p + base);
        uint4 a = q[0], b = q[1];
        unsigned u[8] = {a.x, a.y, a.z, a.w, b.x, b.y, b.z, b.w};
#pragma unroll
        for (int k = 0; k < 8; k++) {
            o[2 * k]     = lo_bf(u[k]);
            o[2 * k + 1] = hi_bf(u[k]);
        }
    }
}

__device__ __forceinline__ void load_edge(const void* __restrict__ ei, int e, int is64,
                                          int& s, int& d) {
    if (is64) {
        const long long* p = (const long long*)ei;
        s = (int)p[e];
        d = (int)p[N_EDGES + e];
    } else {
        const int* p = (const int*)ei;
        s = p[e];
        d = p[N_EDGES + e];
    }
}

// Parallel flag detection: first wave (64 lanes) checks 256 x-values (4 each)
// and the first 16 edge int64s via ballot. Replaces the serial 272-iteration
// lane-0 loop that every block of every kernel was paying (~1k+ cyc/block).
__device__ __forceinline__ void detect_flags_par(const void* x, const void* ei,
                                                 int* flags) {
    int t = threadIdx.x;
    if (t < 64) {
        const ushort_t* h = (const ushort_t*)x;
        int bad = 0;
#pragma unroll
        for (int k = 0; k < 4; k++) {
            float v = bf_bits(h[4 * t + k]);
            if (!(v == v) || fabsf(v) > 1.0e6f) bad = 1;
        }
        unsigned long long mb = __ballot(bad);
        const long long* p = (const long long*)ei;
        int bad64 = 0;
        if (t < 16) {
            long long v = p[t];
            bad64 = (v < 0 || v >= N_NODES) ? 1 : 0;
        }
        unsigned long long m64 = __ballot(bad64);
        if (t == 0) {
            flags[0] = mb ? 1 : 0;
            flags[1] = m64 ? 0 : 1;
        }
    }
}

__device__ __forceinline__ void stage_weights(
    const void* W1, const void* b1, const void* W2, const void* b2, int f32,
    float* sW1, float* sW2t, float* sb1, float* sb2)
{
    int t = threadIdx.x;
    for (int idx = t; idx < HID * 2 * D; idx += blockDim.x)
        sW1[idx] = ld_f(W1, idx, f32);
    for (int idx = t; idx < HID * D; idx += blockDim.x) {
        int j = idx / D, i = idx % D;
        sW2t[idx] = ld_f(W2, i * HID + j, f32);
    }
    if (t < HID) sb1[t] = ld_f(b1, t, f32);
    if (t < D)  sb2[t] = ld_f(b2, t, f32);
}

// ---------------------------------------------------------------------------
// Full-MLP per-edge math, f32 (safety + fallback paths)
// ---------------------------------------------------------------------------
__device__ __forceinline__ void edge_math_v4(
    const float* __restrict__ sW1, const float* __restrict__ sW2t,
    const float* __restrict__ sb1, const float* __restrict__ sb2,
    const float* xs, const float* xd, float coef,
    float* ms, float* md)
{
    float vs[D], vd[D];
#pragma unroll
    for (int i = 0; i < D; i++) { vs[i] = sb2[i]; vd[i] = sb2[i]; }
#pragma unroll 4
    for (int j = 0; j < HID; j++) {
        float hs = sb1[j], hd = sb1[j];
        const float4* w4 = (const float4*)&sW1[j * 2 * D];
#pragma unroll
        for (int t = 0; t < 4; t++) {
            float4 wv = w4[t];
            int k = 4 * t;
            hs = fmaf(wv.x, xs[k],     hs); hd = fmaf(wv.x, xd[k],     hd);
            hs = fmaf(wv.y, xs[k + 1], hs); hd = fmaf(wv.y, xd[k + 1], hd);
            hs = fmaf(wv.z, xs[k + 2], hs); hd = fmaf(wv.z, xd[k + 2], hd);
            hs = fmaf(wv.w, xs[k + 3], hs); hd = fmaf(wv.w, xd[k + 3], hd);
        }
#pragma unroll
        for (int t = 0; t < 4; t++) {
            float4 wv = w4[4 + t];
            int k = 4 * t;
            hs = fmaf(wv.x, xd[k],     hs); hd = fmaf(wv.x, xs[k],     hd);
            hs = fmaf(wv.y, xd[k + 1], hs); hd = fmaf(wv.y, xs[k + 1], hd);
            hs = fmaf(wv.z, xd[k + 2], hs); hd = fmaf(wv.z, xs[k + 2], hd);
            hs = fmaf(wv.w, xd[k + 3], hs); hd = fmaf(wv.w, xs[k + 3], hd);
        }
        hs = fmaxf(hs, 0.0f);
        hd = fmaxf(hd, 0.0f);
        const float4* w24 = (const float4*)&sW2t[j * D];
#pragma unroll
        for (int t = 0; t < 4; t++) {
            float4 u = w24[t];
            int i = 4 * t;
            vs[i]     = fmaf(u.x, hs, vs[i]);     vd[i]     = fmaf(u.x, hd, vd[i]);
            vs[i + 1] = fmaf(u.y, hs, vs[i + 1]); vd[i + 1] = fmaf(u.y, hd, vd[i + 1]);
            vs[i + 2] = fmaf(u.z, hs, vs[i + 2]); vd[i + 2] = fmaf(u.z, hd, vd[i + 2]);
            vs[i + 3] = fmaf(u.w, hs, vs[i + 3]); vd[i + 3] = fmaf(u.w, hd, vd[i + 3]);
        }
    }
    float ns = 0.0f, nd = 0.0f;
#pragma unroll
    for (int i = 0; i < D; i++) { ns = fmaf(vs[i], vs[i], ns); nd = fmaf(vd[i], vd[i], nd); }
    float is_ = 1.0f / fmaxf(sqrtf(ns), 1e-12f);
    float id_ = 1.0f / fmaxf(sqrtf(nd), 1e-12f);
#pragma unroll
    for (int i = 0; i < D; i++) { vs[i] *= is_; vd[i] *= id_; }
    float dot1 = 0.0f;
#pragma unroll
    for (int i = 0; i < D; i++) dot1 = fmaf(vd[i], xd[i], dot1);
#pragma unroll
    for (int i = 0; i < D; i++) ms[i] = fmaf(-2.0f * dot1, vd[i], xd[i]);
    float dot2 = 0.0f;
#pragma unroll
    for (int i = 0; i < D; i++) dot2 = fmaf(vs[i], ms[i], dot2);
#pragma unroll
    for (int i = 0; i < D; i++) ms[i] = coef * fmaf(-2.0f * dot2, vs[i], ms[i]);
    float dot3 = 0.0f;
#pragma unroll
    for (int i = 0; i < D; i++) dot3 = fmaf(vs[i], xs[i], dot3);
#pragma unroll
    for (int i = 0; i < D; i++) md[i] = fmaf(-2.0f * dot3, vs[i], xs[i]);
    float dot4 = 0.0f;
#pragma unroll
    for (int i = 0; i < D; i++) dot4 = fmaf(vd[i], md[i], dot4);
#pragma unroll
    for (int i = 0; i < D; i++) md[i] = coef * fmaf(-2.0f * dot4, vd[i], md[i]);
}

// ===========================================================================
// CSR path kernels
// ===========================================================================
// Counting + (block 0 only) packing the f32 weight table into ws.
__global__ void csr_count_kernel(const void* __restrict__ ei,
                                 const void* __restrict__ x,
                                 const void* __restrict__ W1,
                                 const void* __restrict__ b1,
                                 const void* __restrict__ W2,
                                 const void* __restrict__ b2,
                                 int* __restrict__ wsI) {
    __shared__ int sfl[2];
    detect_flags_par(x, ei, sfl);
    __syncthreads();
    int i64 = sfl[1];

    if (blockIdx.x == 0) {
        // pack f32 weight table (bf16 interpretation; unused by the f32 path)
        float* pf = (float*)(wsI + PREP_OFF);
        const ushort_t* W1b = (const ushort_t*)W1;
        const ushort_t* W2b = (const ushort_t*)W2;
        const ushort_t* b1b = (const ushort_t*)b1;
        const ushort_t* b2b = (const ushort_t*)b2;
        for (int idx = threadIdx.x; idx < 64 * 64; idx += 256) {
            int j = idx >> 6, w = idx & 63;
            float val = 0.0f;
            if (w < 32)      val = bf_bits(W1b[j * 32 + w]);
            else if (w < 48) val = bf_bits(W2b[(w - 32) * HID + j]);
            else if (w == 48) val = bf_bits(b1b[j]);
            pf[idx] = val;
        }
        if (threadIdx.x < D)
            pf[64 * 64 + threadIdx.x] = bf_bits(b2b[threadIdx.x]);
    }

    int e = blockIdx.x * blockDim.x + threadIdx.x;
    if (e >= N_EDGES) return;
    int s, d;
    load_edge(ei, e, i64, s, d);
    int r = (e & 3) * N_NODES;
    atomicAdd(&wsI[CNT4_OFF + r + s], 1);
    atomicAdd(&wsI[CNT4_OFF + r + d], 1);
}

__global__ __launch_bounds__(SCAN_B) void csr_scan1_kernel(int* __restrict__ wsI) {
    __shared__ int sm[SCAN_B];
    int t = threadIdx.x;
    int g = blockIdx.x * SCAN_B + t;
    int c = 0;
    if (g < N_NODES) {
        c = wsI[CNT4_OFF + g] + wsI[CNT4_OFF + N_NODES + g]
          + wsI[CNT4_OFF + 2 * N_NODES + g] + wsI[CNT4_OFF + 3 * N_NODES + g];
        wsI[DEG_OFF + g] = c;
    }
    sm[t] = c;
    __syncthreads();
    for (int st = SCAN_B / 2; st > 0; st >>= 1) {
        if (t < st) sm[t] += sm[t + st];
        __syncthreads();
    }
    if (t == 0) wsI[BS_OFF + blockIdx.x] = sm[0];
}

__global__ __launch_bounds__(SCAN_B) void csr_scan3_kernel(int* __restrict__ wsI) {
    __shared__ int sB[SCAN_B];
    __shared__ int sm[SCAN_B];
    int t = threadIdx.x;
    int bsv = (t < SCAN_G) ? wsI[BS_OFF + t] : 0;
    sB[t] = bsv;
    __syncthreads();
    for (int st = 1; st < SCAN_B; st <<= 1) {
        int u = (t >= st) ? sB[t - st] : 0;
        __syncthreads();
        sB[t] += u;
        __syncthreads();
    }
    int blockBase = sB[blockIdx.x] - wsI[BS_OFF + blockIdx.x];

    int g = blockIdx.x * SCAN_B + t;
    int c = (g < N_NODES) ? wsI[DEG_OFF + g] : 0;
    sm[t] = c;
    __syncthreads();
    for (int st = 1; st < SCAN_B; st <<= 1) {
        int u = (t >= st) ? sm[t - st] : 0;
        __syncthreads();
        sm[t] += u;
        __syncthreads();
    }
    int excl = sm[t] - c + blockBase;
    if (g < N_NODES) {
        wsI[OFF_OFF + g] = excl;
        wsI[CUR_OFF + g] = excl;
        if (g == N_NODES - 1) wsI[OFF_OFF + N_NODES] = excl + c;
    }
}

// ---------------------------------------------------------------------------
// Edge kernel. bf16 path: f32 FMA with SGPR-resident weights.
// Why: v_dot2_f32_f16 measured ~8 cyc/instr (quarter rate) on gfx950 —
// VALU-busy time was a constant ~60 us across R0/R2 (3072 fdot2/edge).
// v_fma_f32 is 2 cyc -> 6144 FMA/edge issues in ~half the time, weights
// stream from the scalar pipe (s_load per j-row, 256B aligned), and h
// stays in f32 (strictly better precision than the RTZ-f16 squeeze).
// ---------------------------------------------------------------------------
__global__ __launch_bounds__(256) void csr_edge_kernel(
    const void* __restrict__ x,
    const void* __restrict__ ei,
    const void* __restrict__ W1,
    const void* __restrict__ b1,
    const void* __restrict__ W2,
    const void* __restrict__ b2,
    const float* __restrict__ prep,
    int* __restrict__ wsI)
{
    __shared__ __align__(16) float sW1f[HID * 2 * D];   // f32 path only
    __shared__ __align__(16) float sW2tf[HID * D];      // f32 path only
    __shared__ float sb1[HID];
    __shared__ float sb2[D];
    __shared__ int sfl[2];

    detect_flags_par(x, ei, sfl);
    __syncthreads();
    int f32 = sfl[0], i64 = sfl[1];
    int t = threadIdx.x;

    if (f32) {
        for (int idx = t; idx < HID * 2 * D; idx += 256)
            sW1f[idx] = ld_f(W1, idx, 1);
        for (int idx = t; idx < HID * D; idx += 256) {
            int j = idx / D, i = idx % D;
            sW2tf[idx] = ld_f(W2, i * HID + j, 1);
        }
        if (t < HID) sb1[t] = ld_f(b1, t, 1);
        if (t < D)  sb2[t] = ld_f(b2, t, 1);
        __syncthreads();
    }

    int e = blockIdx.x * 256 + t;
    if (e >= N_EDGES) return;

    int s, d;
    load_edge(ei, e, i64, s, d);
    float degs = (float)wsI[DEG_OFF + s];
    float degd = (float)wsI[DEG_OFF + d];
    float coef = (1.0f / sqrtf(fmaxf(degs, 1e-5f))) * (1.0f / sqrtf(fmaxf(degd, 1e-5f)));
    float* msg = (float*)(wsI + MSG_OFF_I);

    float xs[D], xd[D];
    load16(x, (long long)s * D, f32, xs);
    load16(x, (long long)d * D, f32, xd);

    float ms[D], md[D];
    if (!f32) {
        const float* b2f = prep + 64 * 64;
        float vs[D], vd[D];
#pragma unroll
        for (int i = 0; i < D; i++) { vs[i] = b2f[i]; vd[i] = b2f[i]; }

#pragma unroll 1
        for (int j = 0; j < HID; j++) {
            const float* w = prep + (j << 6);    // uniform -> s_load
            float b1j = w[48];
            float hs0 = b1j, hs1 = 0.0f, hd0 = b1j, hd1 = 0.0f;
#pragma unroll
            for (int k = 0; k < 8; k++) {        // [xs | .] part
                hs0 = fmaf(w[k],     xs[k],     hs0);
                hd0 = fmaf(w[k],     xd[k],     hd0);
                hs1 = fmaf(w[8 + k], xs[8 + k], hs1);
                hd1 = fmaf(w[8 + k], xd[8 + k], hd1);
            }
#pragma unroll
            for (int k = 0; k < 8; k++) {        // [. | xd] part
                hs0 = fmaf(w[16 + k], xd[k],     hs0);
                hd0 = fmaf(w[16 + k], xs[k],     hd0);
                hs1 = fmaf(w[24 + k], xd[8 + k], hs1);
                hd1 = fmaf(w[24 + k], xs[8 + k], hd1);
            }
            float hs = fmaxf(hs0 + hs1, 0.0f);
            float hd = fmaxf(hd0 + hd1, 0.0f);
#pragma unroll
            for (int i = 0; i < D; i++) {
                vs[i] = fmaf(w[32 + i], hs, vs[i]);
                vd[i] = fmaf(w[32 + i], hd, vd[i]);
            }
        }

        float ns = 0.0f, nd = 0.0f;
#pragma unroll
        for (int i = 0; i < D; i++) { ns = fmaf(vs[i], vs[i], ns); nd = fmaf(vd[i], vd[i], nd); }
        float is_ = 1.0f / fmaxf(sqrtf(ns), 1e-12f);
        float id_ = 1.0f / fmaxf(sqrtf(nd), 1e-12f);
#pragma unroll
        for (int i = 0; i < D; i++) { vs[i] *= is_; vd[i] *= id_; }

        float dot1 = 0.0f;
#pragma unroll
        for (int i = 0; i < D; i++) dot1 = fmaf(vd[i], xd[i], dot1);
#pragma unroll
        for (int i = 0; i < D; i++) ms[i] = fmaf(-2.0f * dot1, vd[i], xd[i]);
        float dot2 = 0.0f;
#pragma unroll
        for (int i = 0; i < D; i++) dot2 = fmaf(vs[i], ms[i], dot2);
#pragma unroll
        for (int i = 0; i < D; i++) ms[i] = coef * fmaf(-2.0f * dot2, vs[i], ms[i]);
        float dot3 = 0.0f;
#pragma unroll
        for (int i = 0; i < D; i++) dot3 = fmaf(vs[i], xs[i], dot3);
#pragma unroll
        for (int i = 0; i < D; i++) md[i] = fmaf(-2.0f * dot3, vs[i], xs[i]);
        float dot4 = 0.0f;
#pragma unroll
        for (int i = 0; i < D; i++) dot4 = fmaf(vd[i], md[i], dot4);
#pragma unroll
        for (int i = 0; i < D; i++) md[i] = coef * fmaf(-2.0f * dot4, vd[i], md[i]);
    } else {
        edge_math_v4(sW1f, sW2tf, sb1, sb2, xs, xd, coef, ms, md);
    }

    int slot_s = atomicAdd(&wsI[CUR_OFF + s], 1);
    float4* m0 = (float4*)(msg + (long long)slot_s * D);
    m0[0] = make_float4(ms[0], ms[1], ms[2], ms[3]);
    m0[1] = make_float4(ms[4], ms[5], ms[6], ms[7]);
    m0[2] = make_float4(ms[8], ms[9], ms[10], ms[11]);
    m0[3] = make_float4(ms[12], ms[13], ms[14], ms[15]);
    int slot_d = atomicAdd(&wsI[CUR_OFF + d], 1);
    float4* m1 = (float4*)(msg + (long long)slot_d * D);
    m1[0] = make_float4(md[0], md[1], md[2], md[3]);
    m1[1] = make_float4(md[4], md[5], md[6], md[7]);
    m1[2] = make_float4(md[8], md[9], md[10], md[11]);
    m1[3] = make_float4(md[12], md[13], md[14], md[15]);
}

// Gather: 4 lanes per node (lane c -> dims 4c..4c+3), unroll-2 accumulation.
__global__ __launch_bounds__(256) void csr_gather_kernel(
    const void* __restrict__ x,
    const void* __restrict__ ei,
    const int* __restrict__ wsI,
    void* __restrict__ out)
{
    __shared__ int sfl[2];
    detect_flags_par(x, ei, sfl);
    __syncthreads();
    int f32 = sfl[0];

    int n = blockIdx.x * 64 + (threadIdx.x >> 2);
    int c = threadIdx.x & 3;
    if (n >= N_NODES) return;

    const int* off = wsI + OFF_OFF;
    const float4* msg4 = (const float4*)(wsI + MSG_OFF_I);

    int beg = off[n], end = off[n + 1];
    float4 a = make_float4(0.0f, 0.0f, 0.0f, 0.0f);
    int it = beg;
    for (; it + 2 <= end; it += 2) {
        float4 u = msg4[(long long)it * 4 + c];
        float4 v = msg4[(long long)(it + 1) * 4 + c];
        a.x += u.x + v.x; a.y += u.y + v.y; a.z += u.z + v.z; a.w += u.w + v.w;
    }
    if (it < end) {
        float4 u = msg4[(long long)it * 4 + c];
        a.x += u.x; a.y += u.y; a.z += u.z; a.w += u.w;
    }

    long long xb = (long long)n * D + 4 * c;
    float4 xv;
    if (f32) {
        xv = *(const float4*)((const float*)x + xb);
    } else {
        uint2 u = *(const uint2*)((const ushort_t*)x + xb);
        xv.x = lo_bf(u.x); xv.y = hi_bf(u.x);
        xv.z = lo_bf(u.y); xv.w = hi_bf(u.y);
    }
    float4 r;
    r.x = fmaxf(xv.x + a.x, 0.0f);
    r.y = fmaxf(xv.y + a.y, 0.0f);
    r.z = fmaxf(xv.z + a.z, 0.0f);
    r.w = fmaxf(xv.w + a.w, 0.0f);
    if (f32) {
        *(float4*)((float*)out + xb) = r;
    } else {
        uint2 o;
        o.x = (unsigned)f2bf(r.x) | ((unsigned)f2bf(r.y) << 16);
        o.y = (unsigned)f2bf(r.z) | ((unsigned)f2bf(r.w) << 16);
        *(uint2*)((ushort_t*)out + xb) = o;
    }
}

// ===========================================================================
// Fallback path (known-good): float atomics into acc
// ===========================================================================
__global__ void fb_init_kernel(float* __restrict__ ws,
                               const void* __restrict__ x,
                               const void* __restrict__ ei) {
    int i = blockIdx.x * blockDim.x + threadIdx.x;
    if (i < FB_FLAGS) ws[i] = 0.0f;
    if (blockIdx.x == 0)
        detect_flags_par(x, ei, (int*)(ws + FB_FLAGS));
}

__global__ void fb_deg_kernel(const void* __restrict__ ei, float* __restrict__ ws) {
    int i64 = ((const int*)(ws + FB_FLAGS))[1];
    int e = blockIdx.x * blockDim.x + threadIdx.x;
    if (e >= N_EDGES) return;
    int s, d;
    load_edge(ei, e, i64, s, d);
    atomicAdd(&ws[s], 1.0f);
    atomicAdd(&ws[d], 1.0f);
}

__global__ __launch_bounds__(256) void fb_edge_kernel(
    const void* __restrict__ x, const void* __restrict__ ei,
    const void* __restrict__ W1, const void* __restrict__ b1,
    const void* __restrict__ W2, const void* __restrict__ b2,
    float* __restrict__ ws)
{
    __shared__ __align__(16) float sW1[HID * 2 * D];
    __shared__ __align__(16) float sW2t[HID * D];
    __shared__ float sb1[HID];
    __shared__ float sb2[D];
    const int* flags = (const int*)(ws + FB_FLAGS);
    int f32 = flags[0], i64 = flags[1];
    stage_weights(W1, b1, W2, b2, f32, sW1, sW2t, sb1, sb2);
    __syncthreads();
    int e = blockIdx.x * blockDim.x + threadIdx.x;
    if (e >= N_EDGES) return;
    int s, d;
    load_edge(ei, e, i64, s, d);
    float xs[D], xd[D];
    load16(x, (long long)s * D, f32, xs);
    load16(x, (long long)d * D, f32, xd);
    float coef = (1.0f / sqrtf(fmaxf(ws[s], 1e-5f))) * (1.0f / sqrtf(fmaxf(ws[d], 1e-5f)));
    float ms[D], md[D];
    edge_math_v4(sW1, sW2t, sb1, sb2, xs, xd, coef, ms, md);
    float* acc = ws + FB_NDEG;
#pragma unroll
    for (int i = 0; i < D; i++) atomicAdd(&acc[(long long)s * D + i], ms[i]);
#pragma unroll
    for (int i = 0; i < D; i++) atomicAdd(&acc[(long long)d * D + i], md[i]);
}

__global__ void fb_finalize_kernel(const void* __restrict__ x,
                                   const float* __restrict__ ws,
                                   void* __restrict__ out)
{
    int f32 = ((const int*)(ws + FB_FLAGS))[0];
    const float* acc = ws + FB_NDEG;
    int i = blockIdx.x * blockDim.x + threadIdx.x;
    if (i >= FB_NACC) return;
    float v = ld_f(x, i, f32) + acc[i];
    v = fmaxf(v, 0.0f);
    if (f32) ((float*)out)[i] = v;
    else     ((__hip_bfloat16*)out)[i] = __float2bfloat16(v);
}

// ===========================================================================
extern "C" void kernel_launch(void* const* d_in, const int* in_sizes, int n_in,
                              void* d_out, int out_size, void* d_ws, size_t ws_size,
                              hipStream_t stream)
{
    const void* x  = d_in[0];
    const void* ei = d_in[1];
    const void* W1 = d_in[2];
    const void* b1 = d_in[3];
    const void* W2 = d_in[4];
    const void* b2 = d_in[5];

    int blk = 256;
    if (ws_size >= CSR_NEEDED_BYTES) {
        int* wsI = (int*)d_ws;
        hipMemsetAsync(d_ws, 0, (size_t)4 * N_NODES * sizeof(int), stream);
        csr_count_kernel<<<(N_EDGES + blk - 1) / blk, blk, 0, stream>>>(ei, x, W1, b1, W2, b2, wsI);
        csr_scan1_kernel<<<SCAN_G, SCAN_B, 0, stream>>>(wsI);
        csr_scan3_kernel<<<SCAN_G, SCAN_B, 0, stream>>>(wsI);
        csr_edge_kernel<<<(N_EDGES + blk - 1) / blk, blk, 0, stream>>>(
            x, ei, W1, b1, W2, b2, (const float*)(wsI + PREP_OFF), wsI);
        csr_gather_kernel<<<(N_NODES + 63) / 64, blk, 0, stream>>>(x, ei, wsI, d_out);
    } else {
        float* ws = (float*)d_ws;
        fb_init_kernel<<<(FB_FLAGS + blk - 1) / blk, blk, 0, stream>>>(ws, x, ei);
        fb_deg_kernel<<<(N_EDGES + blk - 1) / blk, blk, 0, stream>>>(ei, ws);
        fb_edge_kernel<<<(N_EDGES + blk - 1) / blk, blk, 0, stream>>>(x, ei, W1, b1, W2, b2, ws);
        fb_finalize_kernel<<<(FB_NACC + blk - 1) / blk, blk, 0, stream>>>(x, ws, d_out);
    }
}